// Round 5
// baseline (4102.676 us; speedup 1.0000x reference)
//
#include <hip/hip_runtime.h>
#include <hip/hip_bf16.h>
#include <stdint.h>

#define N_CELLS  512
#define N_PIX    25600
#define NBF      100      // n_bins_filter
#define MAXC     20
#define N_FRAMES 300
#define NBT      1500     // n_bins_total
#define N_INIT   100
#define T_STEPS  (NBT - N_INIT)   // 1400

#define RING   104        // time-major ring rows (time mod RING)
#define NWG    64
#define CPW    8          // cells per WG (one worker wave each)
#define WAVES  9          // 8 workers + 1 poller
#define SCAN_THREADS (WAVES * 64)  // 576
#define XDEPTH 8          // exchange ring depth (skew <= 1)

// ---------------- GEMM tiling ----------------
#define GT 64
#define GC 64
#define GK 64
#define KSPLIT 8
#define KCH (N_PIX / KSPLIT)      // 3200

// ============== GEMM partial: part[kb][t][c] = sum_{k in chunk} A[t,k]*B[c,k] ==============
__global__ __launch_bounds__(256) void gemm_partial_k(
        const float* __restrict__ A,   // input_frames [300][25600]
        const float* __restrict__ B,   // spat_filters [512][25600]
        float* __restrict__ part)      // [KSPLIT][300][512]
{
    __shared__ float As[GK][GT + 4];   // transposed: [k][row]
    __shared__ float Bs[GK][GC + 4];
    const int kb = blockIdx.x, tb = blockIdx.y, cb = blockIdx.z;
    const int tid = threadIdx.x;
    const int tx = tid & 15, ty = tid >> 4;
    const int t0 = tb * GT, c0 = cb * GC, k0 = kb * KCH;

    float acc[4][4];
    #pragma unroll
    for (int i = 0; i < 4; ++i)
        #pragma unroll
        for (int j = 0; j < 4; ++j) acc[i][j] = 0.f;

    for (int kc = 0; kc < KCH; kc += GK) {
        #pragma unroll
        for (int p = 0; p < 4; ++p) {
            const int r  = (tid >> 4) + p * 16;
            const int kk = (tid & 15) * 4;
            float4 av = make_float4(0.f, 0.f, 0.f, 0.f);
            if (t0 + r < N_FRAMES)
                av = *(const float4*)&A[(size_t)(t0 + r) * N_PIX + k0 + kc + kk];
            As[kk + 0][r] = av.x; As[kk + 1][r] = av.y;
            As[kk + 2][r] = av.z; As[kk + 3][r] = av.w;
            const float4 bv = *(const float4*)&B[(size_t)(c0 + r) * N_PIX + k0 + kc + kk];
            Bs[kk + 0][r] = bv.x; Bs[kk + 1][r] = bv.y;
            Bs[kk + 2][r] = bv.z; Bs[kk + 3][r] = bv.w;
        }
        __syncthreads();
        #pragma unroll
        for (int kk = 0; kk < GK; ++kk) {
            const float4 a4 = *(const float4*)&As[kk][ty * 4];
            const float4 b4 = *(const float4*)&Bs[kk][tx * 4];
            const float aa[4] = {a4.x, a4.y, a4.z, a4.w};
            const float bb[4] = {b4.x, b4.y, b4.z, b4.w};
            #pragma unroll
            for (int ii = 0; ii < 4; ++ii)
                #pragma unroll
                for (int jj = 0; jj < 4; ++jj)
                    acc[ii][jj] = fmaf(aa[ii], bb[jj], acc[ii][jj]);
        }
        __syncthreads();
    }
    #pragma unroll
    for (int ii = 0; ii < 4; ++ii) {
        const int t = t0 + ty * 4 + ii;
        if (t < N_FRAMES) {
            #pragma unroll
            for (int jj = 0; jj < 4; ++jj)
                part[(size_t)kb * (N_FRAMES * N_CELLS) + (size_t)t * N_CELLS + c0 + tx * 4 + jj] = acc[ii][jj];
        }
    }
}

// ============== reduce split-K partials ==============
__global__ void reduce_part_k(const float* __restrict__ part, float* __restrict__ spat) {
    int i = blockIdx.x * 256 + threadIdx.x;
    if (i < N_FRAMES * N_CELLS) {
        float s = 0.f;
        #pragma unroll
        for (int kb = 0; kb < KSPLIT; ++kb) s += part[(size_t)kb * (N_FRAMES * N_CELLS) + i];
        spat[i] = s;
    }
}

// ============== stim[t][c] = bias[c] + sum_k fw[t,k]*spat[fs[t,k]][c] ==============
__global__ void stim_k(const float* __restrict__ spat, const float* __restrict__ bias,
                       const float* __restrict__ fw, const int* __restrict__ fs,
                       float* __restrict__ stimb) {
    int i = blockIdx.x * 256 + threadIdx.x;
    if (i < NBT * N_CELLS) {
        const int t = i >> 9, c = i & (N_CELLS - 1);
        const int t2 = t * 2;
        float v = bias[c];
        v = fmaf(fw[t2],     spat[(size_t)fs[t2]     * N_CELLS + c], v);
        v = fmaf(fw[t2 + 1], spat[(size_t)fs[t2 + 1] * N_CELLS + c], v);
        stimb[i] = v;
    }
}

// ============== copy initial spikes into out[c][0..99] ==============
__global__ void copy_init_k(const float* __restrict__ ini, float* __restrict__ out) {
    int i = blockIdx.x * 256 + threadIdx.x;
    if (i < N_CELLS * N_INIT) {
        const int c = i / N_INIT;
        const int j = i - c * N_INIT;
        out[(size_t)c * NBT + j] = ini[i];
    }
}

__device__ __forceinline__ int wrapm(int t) {      // t >= -2*RING
    int s = (t + 2 * RING) % RING;
    return s;
}

__device__ __forceinline__ unsigned short f2bf_bits(float v) {
    __hip_bfloat16 h = __float2bfloat16(v);
    return *reinterpret_cast<unsigned short*>(&h);
}
__device__ __forceinline__ float bfbits2f(uint32_t b) {
    return __uint_as_float(b << 16);
}

// ============== persistent scan: single-poller wave, decoupled pipeline ==============
// Exchange word for step s: (uint16)(s+1) << 16 | bf16_bits(spike).
__global__ __launch_bounds__(SCAN_THREADS) void scan_k(
        const float* __restrict__ stimb,  // [1500][512]
        const float* __restrict__ cf,     // [512][20][100]
        const float* __restrict__ ff,     // [512][100]
        const int*   __restrict__ sel,    // [512][20]
        const float* __restrict__ ini,    // [512][100]
        uint32_t* __restrict__ X32,       // [XDEPTH][512] tagged exchange
        float* __restrict__ out)          // [512][1500]
{
    // time-major swizzled ring: entry for (row r, cell c) at ring[r*512 + (c ^ (r&255))]
    __shared__ unsigned short ring[RING * N_CELLS];   // 106496 B
    __shared__ float ns3[3][N_CELLS];                 // f32 spikes, 3-deep time ring

    const int tid  = threadIdx.x;
    const int wave = tid >> 6;
    const int lane = tid & 63;
    const int cell = blockIdx.x * CPW + wave;    // valid for wave < 8

    // ---- worker setup: partial3 coeffs (lags 3..100) + lag1/lag2 duty ----
    int   srcm[MAXC + 1];
    float c1v[MAXC + 1], c2v[MAXC + 1];
    int   src_t = 0;
    float coef_t = 0.f;
    if (wave < CPW) {
        #pragma unroll
        for (int m = 0; m <= MAXC; ++m) {
            const int s = (m < MAXC) ? sel[cell * MAXC + m] : cell;
            const float* f = (m < MAXC) ? (cf + (size_t)(cell * MAXC + m) * NBF)
                                        : (ff + (size_t)cell * NBF);
            srcm[m] = s;
            c1v[m]  = f[97 - lane];                        // lag lane+3 -> idx 97..34
            c2v[m]  = (lane <= 33) ? f[33 - lane] : 0.f;   // lag lane+67 -> idx 33..0
            if (lane == m)      { src_t = s; coef_t = f[99]; }   // lag-1 duty
            if (lane == m + 32) { src_t = s; coef_t = f[98]; }   // lag-2 duty
        }
    }

    // ---- LDS init ----
    for (int idx = tid; idx < RING * N_CELLS; idx += SCAN_THREADS) ring[idx] = 0;
    for (int idx = tid; idx < 3 * N_CELLS; idx += SCAN_THREADS) (&ns3[0][0])[idx] = 0.f;
    __syncthreads();
    for (int idx = tid; idx < N_CELLS * N_INIT; idx += SCAN_THREADS) {
        const int c = idx / N_INIT;
        const int b = idx - c * N_INIT;          // time b-100 in [-100,-1]
        const int r = b - N_INIT + RING;         // rows 4..103
        ring[r * N_CELLS + (c ^ (r & 255))] = f2bf_bits(ini[idx]);
    }
    for (int c = tid; c < N_CELLS; c += SCAN_THREADS) {
        ns3[2][c] = ini[c * N_INIT + 99];        // y_{-1}
        ns3[1][c] = ini[c * N_INIT + 98];        // y_{-2}
    }
    __syncthreads();

    if (wave == CPW) {
        // ================= poller wave =================
        int r  = 0;   // (i-1) % RING at i=1
        int na = 0;   // (i-1) % 3   at i=1
        for (int i = 0; i < T_STEPS; ++i) {
            if (i > 0) {
                const uint32_t* base = X32 + (size_t)((i - 1) & (XDEPTH - 1)) * N_CELLS;
                uint32_t w[8];
                bool ok;
                do {
                    ok = true;
                    #pragma unroll
                    for (int k = 0; k < 8; ++k) {
                        w[k] = __hip_atomic_load(base + lane + 64 * k,
                                                 __ATOMIC_RELAXED, __HIP_MEMORY_SCOPE_AGENT);
                        ok = ok && ((w[k] >> 16) == (uint32_t)i);
                    }
                } while (!__all(ok));
                const int x = r & 255;
                const int rbase = r * N_CELLS;
                #pragma unroll
                for (int k = 0; k < 8; ++k) {
                    const int c = lane + 64 * k;
                    const uint32_t bits = w[k] & 0xffffu;
                    ring[rbase + (c ^ x)] = (unsigned short)bits;
                    ns3[na][c] = bfbits2f(bits);
                }
                r  = (r + 1 == RING) ? 0 : r + 1;
                na = (na + 1 == 3) ? 0 : na + 1;
            }
            __syncthreads();
        }
    } else {
        // ================= worker wave (one cell) =================
        // rows for partial3(step P): r1 = wrap(P-3-lane), r2 = wrap(P-67-lane) (clamped for lane>33)
        int r1 = wrapm(-3 - lane);                          // for P = 0
        int r2 = (lane <= 33) ? wrapm(-67 - lane) : r1;     // dead lanes read a safe row

        // P_cur = partial3(0)
        float P_cur;
        {
            const int b1 = r1 * N_CELLS, x1 = r1 & 255;
            const int b2 = r2 * N_CELLS, x2 = r2 & 255;
            float p = 0.f;
            #pragma unroll
            for (int m = 0; m <= MAXC; ++m) {
                p = fmaf(bfbits2f(ring[b1 + (srcm[m] ^ x1)]), c1v[m], p);
                p = fmaf(bfbits2f(ring[b2 + (srcm[m] ^ x2)]), c2v[m], p);
            }
            #pragma unroll
            for (int off = 32; off; off >>= 1) p += __shfl_xor(p, off, 64);
            P_cur = p;
        }

        int sA = 2;   // (i-1)%3 at i=0 -> y_{i-1} slot
        int sB = 1;   // (i-2)%3 at i=0 -> y_{i-2} slot

        for (int i = 0; i < T_STEPS; ++i) {
            // ---- pre-barrier: stim prefetch + partial3(i+1) ----
            float stim_i = 0.f;
            if (lane == 0) stim_i = stimb[(size_t)(N_INIT - 1 + i) * N_CELLS + cell];

            r1 = (r1 + 1 == RING) ? 0 : r1 + 1;   // wrap(i-2-lane)
            r2 = (r2 + 1 == RING) ? 0 : r2 + 1;
            float P_next;
            {
                const int b1 = r1 * N_CELLS, x1 = r1 & 255;
                const int b2 = r2 * N_CELLS, x2 = r2 & 255;
                float p = 0.f;
                #pragma unroll
                for (int m = 0; m <= MAXC; ++m) {
                    p = fmaf(bfbits2f(ring[b1 + (srcm[m] ^ x1)]), c1v[m], p);
                    p = fmaf(bfbits2f(ring[b2 + (srcm[m] ^ x2)]), c2v[m], p);
                }
                #pragma unroll
                for (int off = 32; off; off >>= 1) p += __shfl_xor(p, off, 64);
                P_next = p;
            }

            __syncthreads();

            // ---- critical: lag-1/lag-2 terms -> sigmoid -> post ----
            const int slot = (lane < 32) ? sA : sB;
            float t = ns3[slot][src_t] * coef_t;   // coef_t == 0 for inactive lanes
            #pragma unroll
            for (int off = 32; off; off >>= 1) t += __shfl_xor(t, off, 64);

            if (lane == 0) {
                const float g = stim_i + P_cur + t;
                const float s = 1.f / (1.f + __expf(-g));
                const uint32_t pw = ((uint32_t)(i + 1) << 16) | (uint32_t)f2bf_bits(s);
                __hip_atomic_store(&X32[(size_t)(i & (XDEPTH - 1)) * N_CELLS + cell], pw,
                                   __ATOMIC_RELAXED, __HIP_MEMORY_SCOPE_AGENT);
                out[(size_t)cell * NBT + N_INIT + i] = s;
            }

            P_cur = P_next;
            sB = sA;
            sA = (sA + 1 == 3) ? 0 : sA + 1;
        }
    }
}

extern "C" void kernel_launch(void* const* d_in, const int* in_sizes, int n_in,
                              void* d_out, int out_size, void* d_ws, size_t ws_size,
                              hipStream_t stream) {
    const float* ini    = (const float*)d_in[0];   // initial_spikes [512][100]
    const float* frames = (const float*)d_in[1];   // input_frames  [300][25600]
    const float* sfil   = (const float*)d_in[2];   // spat_filters  [512][25600]
    const float* ff     = (const float*)d_in[3];   // feedback_filters [512][100]
    const float* cf     = (const float*)d_in[4];   // coupling_filters [512][20][100]
    const float* bias   = (const float*)d_in[5];   // [512][1]
    const float* fw     = (const float*)d_in[6];   // forward_weights [1500][2]
    const int*   sel    = (const int*)d_in[7];     // coupled_sel [512][20]
    const int*   fs     = (const int*)d_in[8];     // forward_sel [1500][2]
    float* out = (float*)d_out;
    float* ws  = (float*)d_ws;

    // ws layout (floats): spat@0 (153600) | stimb@153600 (768000) | X32@921600 (4096 B-equiv) |
    //                     part@153600 (KSPLIT*153600, overlaps stimb+X32; dead after reduce)
    float* spat  = ws;
    float* stimb = ws + 153600;
    uint32_t* X32 = (uint32_t*)(ws + 153600 + 768000);
    float* part  = ws + 153600;

    hipLaunchKernelGGL(gemm_partial_k,
                       dim3(KSPLIT, (N_FRAMES + GT - 1) / GT, N_CELLS / GC), dim3(256), 0, stream,
                       frames, sfil, part);
    hipLaunchKernelGGL(reduce_part_k, dim3((N_FRAMES * N_CELLS + 255) / 256), dim3(256), 0, stream, part, spat);
    hipLaunchKernelGGL(stim_k, dim3((NBT * N_CELLS + 255) / 256), dim3(256), 0, stream, spat, bias, fw, fs, stimb);
    hipMemsetAsync(X32, 0, (size_t)XDEPTH * N_CELLS * sizeof(uint32_t), stream);
    hipLaunchKernelGGL(copy_init_k, dim3((N_CELLS * N_INIT + 255) / 256), dim3(256), 0, stream, ini, out);
    hipLaunchKernelGGL(scan_k, dim3(NWG), dim3(SCAN_THREADS), 0, stream,
                       stimb, cf, ff, sel, ini, X32, out);
}

// Round 6
// 2530.540 us; speedup vs baseline: 1.6213x; 1.6213x over previous
//
#include <hip/hip_runtime.h>
#include <hip/hip_bf16.h>
#include <stdint.h>

#define N_CELLS  512
#define N_PIX    25600
#define NBF      100      // n_bins_filter
#define MAXC     20
#define N_FRAMES 300
#define NBT      1500     // n_bins_total
#define N_INIT   100
#define T_STEPS  (NBT - N_INIT)   // 1400

#define RING   104        // private ring slots (time mod RING)
#define NSRC   (MAXC + 1) // 21 sources (20 coupled + self feedback)

// ---------------- GEMM tiling ----------------
#define GT 64
#define GC 64
#define GK 64
#define KSPLIT 8
#define KCH (N_PIX / KSPLIT)      // 3200

// ============== GEMM partial: part[kb][t][c] = sum_{k in chunk} A[t,k]*B[c,k] ==============
__global__ __launch_bounds__(256) void gemm_partial_k(
        const float* __restrict__ A,   // input_frames [300][25600]
        const float* __restrict__ B,   // spat_filters [512][25600]
        float* __restrict__ part)      // [KSPLIT][300][512]
{
    __shared__ float As[GK][GT + 4];   // transposed: [k][row]
    __shared__ float Bs[GK][GC + 4];
    const int kb = blockIdx.x, tb = blockIdx.y, cb = blockIdx.z;
    const int tid = threadIdx.x;
    const int tx = tid & 15, ty = tid >> 4;
    const int t0 = tb * GT, c0 = cb * GC, k0 = kb * KCH;

    float acc[4][4];
    #pragma unroll
    for (int i = 0; i < 4; ++i)
        #pragma unroll
        for (int j = 0; j < 4; ++j) acc[i][j] = 0.f;

    for (int kc = 0; kc < KCH; kc += GK) {
        #pragma unroll
        for (int p = 0; p < 4; ++p) {
            const int r  = (tid >> 4) + p * 16;
            const int kk = (tid & 15) * 4;
            float4 av = make_float4(0.f, 0.f, 0.f, 0.f);
            if (t0 + r < N_FRAMES)
                av = *(const float4*)&A[(size_t)(t0 + r) * N_PIX + k0 + kc + kk];
            As[kk + 0][r] = av.x; As[kk + 1][r] = av.y;
            As[kk + 2][r] = av.z; As[kk + 3][r] = av.w;
            const float4 bv = *(const float4*)&B[(size_t)(c0 + r) * N_PIX + k0 + kc + kk];
            Bs[kk + 0][r] = bv.x; Bs[kk + 1][r] = bv.y;
            Bs[kk + 2][r] = bv.z; Bs[kk + 3][r] = bv.w;
        }
        __syncthreads();
        #pragma unroll
        for (int kk = 0; kk < GK; ++kk) {
            const float4 a4 = *(const float4*)&As[kk][ty * 4];
            const float4 b4 = *(const float4*)&Bs[kk][tx * 4];
            const float aa[4] = {a4.x, a4.y, a4.z, a4.w};
            const float bb[4] = {b4.x, b4.y, b4.z, b4.w};
            #pragma unroll
            for (int ii = 0; ii < 4; ++ii)
                #pragma unroll
                for (int jj = 0; jj < 4; ++jj)
                    acc[ii][jj] = fmaf(aa[ii], bb[jj], acc[ii][jj]);
        }
        __syncthreads();
    }
    #pragma unroll
    for (int ii = 0; ii < 4; ++ii) {
        const int t = t0 + ty * 4 + ii;
        if (t < N_FRAMES) {
            #pragma unroll
            for (int jj = 0; jj < 4; ++jj)
                part[(size_t)kb * (N_FRAMES * N_CELLS) + (size_t)t * N_CELLS + c0 + tx * 4 + jj] = acc[ii][jj];
        }
    }
}

// ============== reduce split-K partials ==============
__global__ void reduce_part_k(const float* __restrict__ part, float* __restrict__ spat) {
    int i = blockIdx.x * 256 + threadIdx.x;
    if (i < N_FRAMES * N_CELLS) {
        float s = 0.f;
        #pragma unroll
        for (int kb = 0; kb < KSPLIT; ++kb) s += part[(size_t)kb * (N_FRAMES * N_CELLS) + i];
        spat[i] = s;
    }
}

// ============== stim[t][c] = bias[c] + sum_k fw[t,k]*spat[fs[t,k]][c] ==============
__global__ void stim_k(const float* __restrict__ spat, const float* __restrict__ bias,
                       const float* __restrict__ fw, const int* __restrict__ fs,
                       float* __restrict__ stimb) {
    int i = blockIdx.x * 256 + threadIdx.x;
    if (i < NBT * N_CELLS) {
        const int t = i >> 9, c = i & (N_CELLS - 1);
        const int t2 = t * 2;
        float v = bias[c];
        v = fmaf(fw[t2],     spat[(size_t)fs[t2]     * N_CELLS + c], v);
        v = fmaf(fw[t2 + 1], spat[(size_t)fs[t2 + 1] * N_CELLS + c], v);
        stimb[i] = v;
    }
}

// ============== copy initial spikes into out[c][0..99] ==============
__global__ void copy_init_k(const float* __restrict__ ini, float* __restrict__ out) {
    int i = blockIdx.x * 256 + threadIdx.x;
    if (i < N_CELLS * N_INIT) {
        const int c = i / N_INIT;
        const int j = i - c * N_INIT;
        out[(size_t)c * NBT + j] = ini[i];
    }
}

// ============== zero the full exchange buffer ==============
__global__ void zero_x_k(uint32_t* __restrict__ X32, int n) {
    int i = blockIdx.x * 256 + threadIdx.x;
    if (i < n) X32[i] = 0;
}

__device__ __forceinline__ int wrapm(int t) {      // t >= -2*RING
    return (t + 2 * RING) % RING;
}
__device__ __forceinline__ unsigned short f2bf_bits(float v) {
    __hip_bfloat16 h = __float2bfloat16(v);
    return *reinterpret_cast<unsigned short*>(&h);
}
__device__ __forceinline__ float bfbits2f(uint32_t b) {
    return __uint_as_float((b & 0xffffu) << 16);
}
__device__ __forceinline__ uint32_t ald(const uint32_t* p) {
    return __hip_atomic_load(p, __ATOMIC_RELAXED, __HIP_MEMORY_SCOPE_AGENT);
}

// ============== persistent scan: one independent wave per cell ==============
// Exchange word for step s, cell c at X32[s*512+c]: (uint16)(s+1) << 16 | bf16_bits(spike).
// Full-size exchange (no ring reuse) -> unbounded skew safe, no deadlock.
__global__ __launch_bounds__(64) void scan_k(
        const float* __restrict__ stimb,  // [1500][512]
        const float* __restrict__ cf,     // [512][20][100]
        const float* __restrict__ ff,     // [512][100]
        const int*   __restrict__ sel,    // [512][20]
        const float* __restrict__ ini,    // [512][100]
        uint32_t* __restrict__ X32,       // [T_STEPS][512] tagged exchange
        float* __restrict__ out)          // [512][1500]
{
    __shared__ unsigned short ring[NSRC][RING];   // private: my sources' histories

    const int cell = blockIdx.x;
    const int lane = threadIdx.x;

    // ---- per-(m,lane) partial coefficients: lag lane+2 (c1v), lag lane+66 (c2v, lane<=34) ----
    float c1v[NSRC], c2v[NSRC];
    #pragma unroll
    for (int m = 0; m < NSRC; ++m) {
        const float* f = (m < MAXC) ? (cf + (size_t)(cell * MAXC + m) * NBF)
                                    : (ff + (size_t)cell * NBF);
        c1v[m] = f[98 - lane];                        // lag lane+2 -> idx 98..35
        c2v[m] = (lane <= 34) ? f[34 - lane] : 0.f;   // lag lane+66 -> idx 34..0
    }

    // ---- lane-m duty: source id, lag-1 coef, init value, bpermute addr, reg select, poll mask ----
    int   s_mine = 0;
    float lag1c  = 0.f;
    float vinit  = 0.f;
    if (lane < NSRC) {
        s_mine = (lane < MAXC) ? sel[cell * MAXC + lane] : cell;
        const float* f = (lane < MAXC) ? (cf + (size_t)(cell * MAXC + lane) * NBF)
                                       : (ff + (size_t)cell * NBF);
        lag1c = f[99];
        vinit = ini[s_mine * N_INIT + (N_INIT - 1)];
    }
    const int jb = (s_mine & 63) << 2;   // bpermute byte index
    const int kk = s_mine >> 6;          // which of my 8 regs

    uint32_t mask = 0;
    for (int m = 0; m < NSRC; ++m) {
        const int sm = (m < MAXC) ? sel[cell * MAXC + m] : cell;
        if ((sm & 63) == lane) mask |= 1u << (sm >> 6);
    }

    // ---- ring init: zero, then my sources' initial spikes at times -100..-1 ----
    for (int idx = lane; idx < NSRC * RING; idx += 64) (&ring[0][0])[idx] = 0;
    for (int m = 0; m < NSRC; ++m) {
        const int sm = (m < MAXC) ? sel[cell * MAXC + m] : cell;
        for (int b = lane; b < N_INIT; b += 64)
            ring[m][b + 4] = f2bf_bits(ini[sm * N_INIT + b]);   // time b-100 -> slot b+4
    }
    // single wave: program order + lgkmcnt suffice; no barrier needed

    int s1 = wrapm(-2 - lane);                       // slot(time i-2-lane) at i=0
    int s2 = (lane <= 34) ? wrapm(-66 - lane) : s1;  // dead lanes shadow s1
    int wslot = 0;                                   // slot(time i-1) at i=1

    for (int i = 0; i < T_STEPS; ++i) {
        // ---- slack: partial over lags 2..100 (times <= i-2, all in ring) ----
        float p = 0.f;
        #pragma unroll
        for (int m = 0; m < NSRC; ++m) {
            p = fmaf(bfbits2f(ring[m][s1]), c1v[m], p);
            p = fmaf(bfbits2f(ring[m][s2]), c2v[m], p);
        }
        #pragma unroll
        for (int off = 32; off; off >>= 1) p += __shfl_xor(p, off, 64);

        const float stim_i = stimb[(size_t)(N_INIT - 1 + i) * N_CELLS + cell];

        // ---- poll my 21 sources' step-(i-1) words (coalesced row load, masked gate) ----
        uint32_t raw = 0;
        float vm;
        if (i > 0) {
            const uint32_t tg = (uint32_t)i;
            const uint32_t* row = X32 + (size_t)(i - 1) * N_CELLS + lane;
            uint32_t w0, w1, w2, w3, w4, w5, w6, w7;
            bool ok;
            do {
                w0 = ald(row);       w1 = ald(row + 64);  w2 = ald(row + 128); w3 = ald(row + 192);
                w4 = ald(row + 256); w5 = ald(row + 320); w6 = ald(row + 384); w7 = ald(row + 448);
                ok = (!(mask & 1u)   || (w0 >> 16) == tg) &&
                     (!(mask & 2u)   || (w1 >> 16) == tg) &&
                     (!(mask & 4u)   || (w2 >> 16) == tg) &&
                     (!(mask & 8u)   || (w3 >> 16) == tg) &&
                     (!(mask & 16u)  || (w4 >> 16) == tg) &&
                     (!(mask & 32u)  || (w5 >> 16) == tg) &&
                     (!(mask & 64u)  || (w6 >> 16) == tg) &&
                     (!(mask & 128u) || (w7 >> 16) == tg);
            } while (!__all(ok));

            // ---- extract my source's value: cross-lane pull + 8->1 select ----
            const uint32_t t0 = (uint32_t)__builtin_amdgcn_ds_bpermute(jb, (int)w0);
            const uint32_t t1 = (uint32_t)__builtin_amdgcn_ds_bpermute(jb, (int)w1);
            const uint32_t t2 = (uint32_t)__builtin_amdgcn_ds_bpermute(jb, (int)w2);
            const uint32_t t3 = (uint32_t)__builtin_amdgcn_ds_bpermute(jb, (int)w3);
            const uint32_t t4 = (uint32_t)__builtin_amdgcn_ds_bpermute(jb, (int)w4);
            const uint32_t t5 = (uint32_t)__builtin_amdgcn_ds_bpermute(jb, (int)w5);
            const uint32_t t6 = (uint32_t)__builtin_amdgcn_ds_bpermute(jb, (int)w6);
            const uint32_t t7 = (uint32_t)__builtin_amdgcn_ds_bpermute(jb, (int)w7);
            const uint32_t a01 = (kk & 1) ? t1 : t0;
            const uint32_t a23 = (kk & 1) ? t3 : t2;
            const uint32_t a45 = (kk & 1) ? t5 : t4;
            const uint32_t a67 = (kk & 1) ? t7 : t6;
            const uint32_t b03 = (kk & 2) ? a23 : a01;
            const uint32_t b47 = (kk & 2) ? a67 : a45;
            raw = ((kk & 4) ? b47 : b03) & 0xffffu;
            vm = bfbits2f(raw);
        } else {
            vm = vinit;
        }

        // ---- critical tail: lag-1 term -> sigmoid -> tagged post ----
        float term = vm * lag1c;    // lag1c == 0 for lanes >= 21
        #pragma unroll
        for (int off = 32; off; off >>= 1) term += __shfl_xor(term, off, 64);

        if (lane == 0) {
            const float g = stim_i + p + term;
            const float sgm = 1.f / (1.f + __expf(-g));
            const uint32_t pw = ((uint32_t)(i + 1) << 16) | (uint32_t)f2bf_bits(sgm);
            __hip_atomic_store(&X32[(size_t)i * N_CELLS + cell], pw,
                               __ATOMIC_RELAXED, __HIP_MEMORY_SCOPE_AGENT);
            out[(size_t)cell * NBT + N_INIT + i] = sgm;
        }

        // ---- slack: append time i-1 to private ring ----
        if (i > 0) {
            if (lane < NSRC) ring[lane][wslot] = (unsigned short)raw;
            wslot = (wslot + 1 == RING) ? 0 : wslot + 1;
        }
        s1 = (s1 + 1 == RING) ? 0 : s1 + 1;
        s2 = (s2 + 1 == RING) ? 0 : s2 + 1;
    }
}

extern "C" void kernel_launch(void* const* d_in, const int* in_sizes, int n_in,
                              void* d_out, int out_size, void* d_ws, size_t ws_size,
                              hipStream_t stream) {
    const float* ini    = (const float*)d_in[0];   // initial_spikes [512][100]
    const float* frames = (const float*)d_in[1];   // input_frames  [300][25600]
    const float* sfil   = (const float*)d_in[2];   // spat_filters  [512][25600]
    const float* ff     = (const float*)d_in[3];   // feedback_filters [512][100]
    const float* cf     = (const float*)d_in[4];   // coupling_filters [512][20][100]
    const float* bias   = (const float*)d_in[5];   // [512][1]
    const float* fw     = (const float*)d_in[6];   // forward_weights [1500][2]
    const int*   sel    = (const int*)d_in[7];     // coupled_sel [512][20]
    const int*   fs     = (const int*)d_in[8];     // forward_sel [1500][2]
    float* out = (float*)d_out;
    float* ws  = (float*)d_ws;

    // ws layout (floats):
    //   spat  @ 0       (153600)
    //   stimb @ 153600  (768000)
    //   X32   @ 921600  (T_STEPS*512 u32 = 716800 words)  [total 1638400 floats = 6.55 MB]
    //   part  @ 153600  (KSPLIT*153600 = 1228800, overlaps stimb+X32; dead after reduce)
    float* spat  = ws;
    float* stimb = ws + 153600;
    uint32_t* X32 = (uint32_t*)(ws + 153600 + 768000);
    float* part  = ws + 153600;
    const int xn = T_STEPS * N_CELLS;   // 716800

    hipLaunchKernelGGL(gemm_partial_k,
                       dim3(KSPLIT, (N_FRAMES + GT - 1) / GT, N_CELLS / GC), dim3(256), 0, stream,
                       frames, sfil, part);
    hipLaunchKernelGGL(reduce_part_k, dim3((N_FRAMES * N_CELLS + 255) / 256), dim3(256), 0, stream, part, spat);
    hipLaunchKernelGGL(stim_k, dim3((NBT * N_CELLS + 255) / 256), dim3(256), 0, stream, spat, bias, fw, fs, stimb);
    hipLaunchKernelGGL(zero_x_k, dim3((xn + 255) / 256), dim3(256), 0, stream, X32, xn);
    hipLaunchKernelGGL(copy_init_k, dim3((N_CELLS * N_INIT + 255) / 256), dim3(256), 0, stream, ini, out);
    hipLaunchKernelGGL(scan_k, dim3(N_CELLS), dim3(64), 0, stream,
                       stimb, cf, ff, sel, ini, X32, out);
}